// Round 1
// baseline (157.440 us; speedup 1.0000x reference)
//
#include <hip/hip_runtime.h>

// PatcherUnfold: y[b,l,e] = sum_k patches[b,l,k] * W[e,k] + bias[e]
//   x: [64,3,384,384] f32, patches: unfold 16x16 -> [64,576,768], W: [768,768], b: [768]
// Implicit GEMM, M=36864 N=768 K=768, bf16 MFMA 16x16x32, fp32 accum.

namespace {

constexpr int PB   = 16;      // patch
constexpr int Cch  = 3;
constexpr int Him  = 384;
constexpr int Wim  = 384;
constexpr int GWp  = 24;      // grid of patches per row
constexpr int Lp   = 576;     // patches per image
constexpr int Kd   = 768;
constexpr int Nd   = 768;
constexpr int Md   = 64 * Lp; // 36864
constexpr int BM   = 128;
constexpr int BN   = 128;
constexpr int BK   = 64;

typedef __bf16 bf16x4 __attribute__((ext_vector_type(4)));
typedef __bf16 bf16x8 __attribute__((ext_vector_type(8)));
typedef float  f32x4  __attribute__((ext_vector_type(4)));

__global__ __launch_bounds__(256, 2)
void patch_embed_gemm(const float* __restrict__ x,
                      const float* __restrict__ Wm,
                      const float* __restrict__ bias,
                      float* __restrict__ out)
{
    // A-tile [128][64] bf16 + B-tile [128][64] bf16, row stride 128 B, XOR-swizzled
    __shared__ __align__(16) unsigned char lds[2 * BM * BK * 2]; // 32 KiB
    unsigned char* const ldsA = lds;
    unsigned char* const ldsB = lds + BM * BK * 2;

    const int tid  = threadIdx.x;
    const int bn   = blockIdx.x;   // 0..5   (N tiles)
    const int bm   = blockIdx.y;   // 0..287 (M tiles)
    const int lane = tid & 63;
    const int wv   = tid >> 6;
    const int wr   = wv >> 1;      // wave row (0..1) -> 64-row strip
    const int wc   = wv & 1;       // wave col (0..1) -> 64-col strip

    // ---- staging map: chunk i = it*256 + tid ; row r = i>>4 (=r0+16*it) ; q = i&15
    const int q    = tid & 15;     // col-chunk (4 floats)
    const int r0   = tid >> 4;     // 0..15
    const int px   = (q & 3) * 4;  // col within 16-wide patch row
    const int pyo  = q >> 2;       // patch-row offset 0..3
    const int swzx = (r0 & 7) << 4;

    // per-row unfold base offsets (K-step invariant): x[b][.][gy*16][gx*16]
    int arow[8];
    #pragma unroll
    for (int it = 0; it < 8; ++it) {
        const int m  = bm * BM + r0 + it * 16;
        const int b  = m / Lp;
        const int l  = m - b * Lp;
        const int gy = l / GWp;
        const int gx = l - gy * GWp;
        arow[it] = b * (Cch * Him * Wim) + (gy * PB) * Wim + gx * PB;
    }
    // LDS write byte offset (same for A and B tiles); +it*2048 per 16 rows
    const int ldsw = r0 * (BK * 2) + ((q * 8) ^ swzx);
    // B (=W) staging source: rows e = bn*128 + r0 + it*16, cols t*64 + q*4 ..
    const int brow = (bn * BN + r0) * Kd + q * 4;

    f32x4 acc[4][4];
    #pragma unroll
    for (int i = 0; i < 4; ++i)
        #pragma unroll
        for (int j = 0; j < 4; ++j)
            acc[i][j] = f32x4{0.f, 0.f, 0.f, 0.f};

    const int fr = lane & 15;  // fragment row/col within 16
    const int kg = lane >> 4;  // k-group 0..3

    for (int t = 0; t < Kd / BK; ++t) {
        // k0 = t*64: channel c = k0/256 fixed, patch-rows pyb..pyb+3
        const int c   = t >> 2;
        const int pyb = (t & 3) * 4;
        const float* xsrc = x + c * (Him * Wim) + (pyb + pyo) * Wim + px;
        const float* wsrc = Wm + t * BK + brow;

        __syncthreads();   // previous MFMA reads done before overwrite
        #pragma unroll
        for (int it = 0; it < 8; ++it) {
            const f32x4 va = *(const f32x4*)(xsrc + arow[it]);
            const f32x4 vb = *(const f32x4*)(wsrc + it * (16 * Kd));
            bf16x4 ha, hb;
            #pragma unroll
            for (int e = 0; e < 4; ++e) {
                ha[e] = (__bf16)va[e];
                hb[e] = (__bf16)vb[e];
            }
            *(bf16x4*)(ldsA + ldsw + it * 2048) = ha;
            *(bf16x4*)(ldsB + ldsw + it * 2048) = hb;
        }
        __syncthreads();

        #pragma unroll
        for (int kk = 0; kk < 2; ++kk) {
            bf16x8 ar[4], br[4];
            const int kb = kk * 64 + kg * 16;  // byte offset of this lane's 8 bf16
            #pragma unroll
            for (int f = 0; f < 4; ++f) {
                const int rowA = wr * 64 + f * 16 + fr;
                ar[f] = *(const bf16x8*)(ldsA + rowA * 128 + (kb ^ ((rowA & 7) << 4)));
                const int rowB = wc * 64 + f * 16 + fr;
                br[f] = *(const bf16x8*)(ldsB + rowB * 128 + (kb ^ ((rowB & 7) << 4)));
            }
            #pragma unroll
            for (int fi = 0; fi < 4; ++fi)
                #pragma unroll
                for (int fj = 0; fj < 4; ++fj)
                    acc[fi][fj] = __builtin_amdgcn_mfma_f32_16x16x32_bf16(
                        ar[fi], br[fj], acc[fi][fj], 0, 0, 0);
        }
    }

    // epilogue: C/D layout col = lane&15, row = (lane>>4)*4 + j  (m89-verified)
    const int orow0 = bm * BM + wr * 64;
    const int ocol0 = bn * BN + wc * 64;
    #pragma unroll
    for (int fj = 0; fj < 4; ++fj) {
        const int col = ocol0 + fj * 16 + fr;
        const float bv = bias[col];
        #pragma unroll
        for (int fi = 0; fi < 4; ++fi) {
            const int row = orow0 + fi * 16 + kg * 4;
            #pragma unroll
            for (int j = 0; j < 4; ++j)
                out[(row + j) * Nd + col] = acc[fi][fj][j] + bv;
        }
    }
}

} // namespace

extern "C" void kernel_launch(void* const* d_in, const int* in_sizes, int n_in,
                              void* d_out, int out_size, void* d_ws, size_t ws_size,
                              hipStream_t stream)
{
    (void)in_sizes; (void)n_in; (void)out_size; (void)d_ws; (void)ws_size;
    const float* x  = (const float*)d_in[0];
    const float* Wm = (const float*)d_in[1];
    const float* bs = (const float*)d_in[2];
    float* out = (float*)d_out;

    dim3 grid(Nd / BN, Md / BM);  // (6, 288)
    patch_embed_gemm<<<grid, dim3(256), 0, stream>>>(x, Wm, bs, out);
}

// Round 2
// 126.756 us; speedup vs baseline: 1.2421x; 1.2421x over previous
//
#include <hip/hip_runtime.h>

// PatcherUnfold: y[b,l,e] = sum_k patches[b,l,k] * W[e,k] + bias[e]
//   x: [64,3,384,384] f32, unfold 16x16 -> [36864, 768]; W: [768,768]; b: [768]
// Implicit GEMM, M=36864 N=768 K=768, bf16 MFMA 16x16x32, fp32 accum.
// Round 2: software-pipelined (prefetch t+1 into regs under MFMA of t),
// double-buffered LDS, single barrier per K-step.

namespace {

constexpr int PB   = 16;
constexpr int Cch  = 3;
constexpr int Him  = 384;
constexpr int Wim  = 384;
constexpr int GWp  = 24;
constexpr int Lp   = 576;
constexpr int Kd   = 768;
constexpr int Nd   = 768;
constexpr int Md   = 64 * Lp;
constexpr int BM   = 128;
constexpr int BN   = 128;
constexpr int BK   = 64;
constexpr int NT   = Kd / BK;        // 12
constexpr int BUFB = BM * BK * 2 * 2; // 32 KiB per double-buffer slot (A+B)

typedef __bf16 bf16x4 __attribute__((ext_vector_type(4)));
typedef __bf16 bf16x8 __attribute__((ext_vector_type(8)));
typedef float  f32x4  __attribute__((ext_vector_type(4)));

__global__ __launch_bounds__(256, 2)
void patch_embed_gemm(const float* __restrict__ x,
                      const float* __restrict__ Wm,
                      const float* __restrict__ bias,
                      float* __restrict__ out)
{
    // [buf 0/1][ A:128x64 bf16 | B:128x64 bf16 ], rows XOR-swizzled
    __shared__ __align__(16) unsigned char lds[2 * BUFB]; // 64 KiB

    const int tid  = threadIdx.x;
    const int bn   = blockIdx.x;   // 0..5
    const int bm   = blockIdx.y;   // 0..287
    const int lane = tid & 63;
    const int wv   = tid >> 6;
    const int wr   = wv >> 1;
    const int wc   = wv & 1;
    const int fr   = lane & 15;
    const int kg   = lane >> 4;

    // staging map: thread handles rows r0+16*it, 4-float chunk q
    const int q    = tid & 15;
    const int r0   = tid >> 4;
    const int px   = (q & 3) * 4;
    const int pyo  = q >> 2;
    const int ldsw = r0 * 128 + ((q * 8) ^ ((r0 & 7) << 4));

    int arow[8];
    #pragma unroll
    for (int it = 0; it < 8; ++it) {
        const int m  = bm * BM + r0 + it * 16;
        const int b  = m / Lp;
        const int l  = m - b * Lp;
        const int gy = l / GWp;
        const int gx = l - gy * GWp;
        arow[it] = b * (Cch * Him * Wim) + (gy * PB) * Wim + gx * PB;
    }
    const int brow = (bn * BN + r0) * Kd + q * 4;

    f32x4 pa[8], pb[8];

    auto load_tile = [&](int t) {
        const int c   = t >> 2;
        const int pyb = (t & 3) * 4;
        const float* xs = x + c * (Him * Wim) + (pyb + pyo) * Wim + px;
        const float* ws = Wm + t * BK + brow;
        #pragma unroll
        for (int it = 0; it < 8; ++it) {
            pa[it] = *(const f32x4*)(xs + arow[it]);
            pb[it] = *(const f32x4*)(ws + it * (16 * Kd));
        }
    };

    auto store_tile = [&](int buf) {
        unsigned char* dst = lds + buf * BUFB;
        #pragma unroll
        for (int it = 0; it < 8; ++it) {
            bf16x4 ha, hb;
            #pragma unroll
            for (int e = 0; e < 4; ++e) {
                ha[e] = (__bf16)pa[it][e];
                hb[e] = (__bf16)pb[it][e];
            }
            *(bf16x4*)(dst + ldsw + it * 2048)         = ha;
            *(bf16x4*)(dst + 16384 + ldsw + it * 2048) = hb;
        }
    };

    f32x4 acc[4][4];
    #pragma unroll
    for (int i = 0; i < 4; ++i)
        #pragma unroll
        for (int j = 0; j < 4; ++j)
            acc[i][j] = f32x4{0.f, 0.f, 0.f, 0.f};

    auto compute = [&](int buf) {
        const unsigned char* ldsA = lds + buf * BUFB;
        const unsigned char* ldsB = ldsA + 16384;
        #pragma unroll
        for (int kk = 0; kk < 2; ++kk) {
            bf16x8 ar[4], br[4];
            const int kb = kk * 64 + kg * 16;
            #pragma unroll
            for (int f = 0; f < 4; ++f) {
                const int rowA = wr * 64 + f * 16 + fr;
                ar[f] = *(const bf16x8*)(ldsA + rowA * 128 + (kb ^ ((rowA & 7) << 4)));
                const int rowB = wc * 64 + f * 16 + fr;
                br[f] = *(const bf16x8*)(ldsB + rowB * 128 + (kb ^ ((rowB & 7) << 4)));
            }
            #pragma unroll
            for (int fi = 0; fi < 4; ++fi)
                #pragma unroll
                for (int fj = 0; fj < 4; ++fj)
                    acc[fi][fj] = __builtin_amdgcn_mfma_f32_16x16x32_bf16(
                        ar[fi], br[fj], acc[fi][fj], 0, 0, 0);
        }
    };

    // ---- pipelined main loop: 1 barrier per K-step ----
    load_tile(0);
    store_tile(0);
    __syncthreads();
    int cur = 0;
    for (int t = 0; t < NT - 1; ++t) {
        load_tile(t + 1);      // issue; vmcnt wait lands after compute()
        compute(cur);
        store_tile(cur ^ 1);
        __syncthreads();
        cur ^= 1;
    }
    compute(cur);

    // epilogue: C/D layout col = lane&15, row = (lane>>4)*4 + j
    const int orow0 = bm * BM + wr * 64;
    const int ocol0 = bn * BN + wc * 64;
    #pragma unroll
    for (int fj = 0; fj < 4; ++fj) {
        const int col = ocol0 + fj * 16 + fr;
        const float bv = bias[col];
        #pragma unroll
        for (int fi = 0; fi < 4; ++fi) {
            const int row = orow0 + fi * 16 + kg * 4;
            #pragma unroll
            for (int j = 0; j < 4; ++j)
                out[(row + j) * Nd + col] = acc[fi][fj][j] + bv;
        }
    }
}

} // namespace

extern "C" void kernel_launch(void* const* d_in, const int* in_sizes, int n_in,
                              void* d_out, int out_size, void* d_ws, size_t ws_size,
                              hipStream_t stream)
{
    (void)in_sizes; (void)n_in; (void)out_size; (void)d_ws; (void)ws_size;
    const float* x  = (const float*)d_in[0];
    const float* Wm = (const float*)d_in[1];
    const float* bs = (const float*)d_in[2];
    float* out = (float*)d_out;

    dim3 grid(Nd / BN, Md / BM);  // (6, 288)
    patch_embed_gemm<<<grid, dim3(256), 0, stream>>>(x, Wm, bs, out);
}

// Round 3
// 78.127 us; speedup vs baseline: 2.0152x; 1.6224x over previous
//
#include <hip/hip_runtime.h>

// PatcherUnfold: y[b,l,e] = sum_k patches[b,l,k] * W[e,k] + bias[e]
//   x: [64,3,384,384] f32, unfold 16x16 -> [36864, 768]; W: [768,768]; b: [768]
// Implicit GEMM, M=36864 N=768 K=768, bf16 MFMA 16x16x32, fp32 accum.
// Round 3: 256x256 tile (8 waves), XCD-chunked block swizzle so same-A-panel
// blocks share an XCD L2; reg-prefetch pipeline, dbuf LDS, 1 barrier/K-step.

namespace {

constexpr int PB   = 16;
constexpr int Cch  = 3;
constexpr int Him  = 384;
constexpr int Wim  = 384;
constexpr int GWp  = 24;
constexpr int Lp   = 576;
constexpr int Kd   = 768;
constexpr int Nd   = 768;
constexpr int Md   = 64 * Lp;      // 36864
constexpr int BM   = 256;
constexpr int BN   = 256;
constexpr int BK   = 64;
constexpr int NT   = Kd / BK;      // 12
constexpr int ASZ  = BM * BK * 2;  // 32 KiB (A half of one buffer)
constexpr int BUFB = 2 * ASZ;      // 64 KiB per pipeline slot (A+B)
constexpr int GN   = Nd / BN;      // 3
constexpr int NBLK = (Md / BM) * GN; // 432 = 8 * 54

typedef __bf16 bf16x4 __attribute__((ext_vector_type(4)));
typedef __bf16 bf16x8 __attribute__((ext_vector_type(8)));
typedef float  f32x4  __attribute__((ext_vector_type(4)));

__global__ __launch_bounds__(512, 2)
void patch_embed_gemm(const float* __restrict__ x,
                      const float* __restrict__ Wm,
                      const float* __restrict__ bias,
                      float* __restrict__ out)
{
    __shared__ __align__(16) unsigned char lds[2 * BUFB]; // 128 KiB

    // XCD-chunked swizzle (NBLK % 8 == 0 -> bijective): XCD k gets logical
    // ids [k*54, (k+1)*54) in bm-major order -> same-bm trios share one L2.
    const int h  = blockIdx.x;
    const int l  = (h & 7) * (NBLK / 8) + (h >> 3);
    const int bm = l / GN;
    const int bn = l - bm * GN;

    const int tid  = threadIdx.x;
    const int lane = tid & 63;
    const int wv   = tid >> 6;   // 0..7
    const int wr   = wv >> 2;    // 0..1  -> 128-row strip
    const int wc   = wv & 3;     // 0..3  -> 64-col strip
    const int fr   = lane & 15;
    const int kg   = lane >> 4;

    // staging map: thread covers rows r0 + 32*it (it=0..7), 4-float chunk q
    const int q    = tid & 15;
    const int r0   = tid >> 4;   // 0..31
    const int px   = (q & 3) * 4;
    const int pyo  = q >> 2;
    const int ldsw = r0 * 128 + ((q * 8) ^ ((r0 & 7) << 4));

    int arow[8];
    #pragma unroll
    for (int it = 0; it < 8; ++it) {
        const int m  = bm * BM + r0 + it * 32;
        const int b  = m / Lp;
        const int li = m - b * Lp;
        const int gy = li / GWp;
        const int gx = li - gy * GWp;
        arow[it] = b * (Cch * Him * Wim) + (gy * PB) * Wim + gx * PB;
    }
    const int brow = (bn * BN + r0) * Kd + q * 4;

    f32x4 pa[8], pb[8];

    auto load_tile = [&](int t) {
        const int c   = t >> 2;
        const int pyb = (t & 3) * 4;
        const float* xs = x + c * (Him * Wim) + (pyb + pyo) * Wim + px;
        const float* ws = Wm + t * BK + brow;
        #pragma unroll
        for (int it = 0; it < 8; ++it) {
            pa[it] = *(const f32x4*)(xs + arow[it]);
            pb[it] = *(const f32x4*)(ws + it * (32 * Kd));
        }
    };

    auto store_tile = [&](int buf) {
        unsigned char* dst = lds + buf * BUFB;
        #pragma unroll
        for (int it = 0; it < 8; ++it) {
            bf16x4 ha, hb;
            #pragma unroll
            for (int e = 0; e < 4; ++e) {
                ha[e] = (__bf16)pa[it][e];
                hb[e] = (__bf16)pb[it][e];
            }
            *(bf16x4*)(dst + ldsw + it * 4096)       = ha;
            *(bf16x4*)(dst + ASZ + ldsw + it * 4096) = hb;
        }
    };

    f32x4 acc[8][4];
    #pragma unroll
    for (int i = 0; i < 8; ++i)
        #pragma unroll
        for (int j = 0; j < 4; ++j)
            acc[i][j] = f32x4{0.f, 0.f, 0.f, 0.f};

    auto compute = [&](int buf) {
        const unsigned char* ldsA = lds + buf * BUFB;
        const unsigned char* ldsB = ldsA + ASZ;
        #pragma unroll
        for (int kk = 0; kk < 2; ++kk) {
            const int kb = kk * 64 + kg * 16;
            bf16x8 br[4];
            #pragma unroll
            for (int f = 0; f < 4; ++f) {
                const int rowB = wc * 64 + f * 16 + fr;
                br[f] = *(const bf16x8*)(ldsB + rowB * 128 + (kb ^ ((rowB & 7) << 4)));
            }
            #pragma unroll
            for (int fi = 0; fi < 8; ++fi) {
                const int rowA = wr * 128 + fi * 16 + fr;
                const bf16x8 ar =
                    *(const bf16x8*)(ldsA + rowA * 128 + (kb ^ ((rowA & 7) << 4)));
                #pragma unroll
                for (int fj = 0; fj < 4; ++fj)
                    acc[fi][fj] = __builtin_amdgcn_mfma_f32_16x16x32_bf16(
                        ar, br[fj], acc[fi][fj], 0, 0, 0);
            }
        }
    };

    // ---- pipelined main loop: 1 barrier per K-step ----
    load_tile(0);
    store_tile(0);
    __syncthreads();
    int cur = 0;
    for (int t = 0; t < NT - 1; ++t) {
        load_tile(t + 1);      // issue; vmcnt wait lands after compute()
        compute(cur);
        store_tile(cur ^ 1);
        __syncthreads();
        cur ^= 1;
    }
    compute(cur);

    // epilogue: C/D layout col = lane&15, row = (lane>>4)*4 + j
    const int orow0 = bm * BM + wr * 128;
    const int ocol0 = bn * BN + wc * 64;
    #pragma unroll
    for (int fj = 0; fj < 4; ++fj) {
        const int col = ocol0 + fj * 16 + fr;
        const float bv = bias[col];
        #pragma unroll
        for (int fi = 0; fi < 8; ++fi) {
            const int row = orow0 + fi * 16 + kg * 4;
            #pragma unroll
            for (int j = 0; j < 4; ++j)
                out[(row + j) * Nd + col] = acc[fi][fj][j] + bv;
        }
    }
}

} // namespace

extern "C" void kernel_launch(void* const* d_in, const int* in_sizes, int n_in,
                              void* d_out, int out_size, void* d_ws, size_t ws_size,
                              hipStream_t stream)
{
    (void)in_sizes; (void)n_in; (void)out_size; (void)d_ws; (void)ws_size;
    const float* x  = (const float*)d_in[0];
    const float* Wm = (const float*)d_in[1];
    const float* bs = (const float*)d_in[2];
    float* out = (float*)d_out;

    patch_embed_gemm<<<dim3(NBLK), dim3(512), 0, stream>>>(x, Wm, bs, out);
}

// Round 4
// 75.243 us; speedup vs baseline: 2.0924x; 1.0383x over previous
//
#include <hip/hip_runtime.h>

// PatcherUnfold: y[b,l,e] = sum_k patches[b,l,k] * W[e,k] + bias[e]
// Implicit GEMM, M=36864 N=768 K=768, bf16 MFMA 16x16x32, fp32 accum.
// Round 4: pre-convert W->bf16 (d_ws); B staged via global_load_lds w=16 with
// pre-swizzled global source (linear LDS dest); A reg-staged fp32->bf16;
// XCD-chunked swizzle; dbuf LDS; 1 barrier/K-step; setprio around MFMA.

namespace {

constexpr int PB   = 16;
constexpr int Cch  = 3;
constexpr int Him  = 384;
constexpr int Wim  = 384;
constexpr int GWp  = 24;
constexpr int Lp   = 576;
constexpr int Kd   = 768;
constexpr int Nd   = 768;
constexpr int Md   = 64 * Lp;      // 36864
constexpr int BM   = 256;
constexpr int BN   = 256;
constexpr int BK   = 64;
constexpr int NT   = Kd / BK;      // 12
constexpr int ASZ  = BM * BK * 2;  // 32 KiB
constexpr int BSZ  = BN * BK * 2;  // 32 KiB
constexpr int BUFB = ASZ + BSZ;    // 64 KiB per pipeline slot
constexpr int GN   = Nd / BN;      // 3
constexpr int NBLK = (Md / BM) * GN; // 432 = 8 * 54

typedef __bf16 bf16x4 __attribute__((ext_vector_type(4)));
typedef __bf16 bf16x8 __attribute__((ext_vector_type(8)));
typedef float  f32x4  __attribute__((ext_vector_type(4)));

__global__ __launch_bounds__(256)
void convert_w(const float* __restrict__ Wm, __bf16* __restrict__ Wb)
{
    const int i = (blockIdx.x * 256 + threadIdx.x) * 4;
    const f32x4 v = *(const f32x4*)(Wm + i);
    bf16x4 h;
    #pragma unroll
    for (int e = 0; e < 4; ++e) h[e] = (__bf16)v[e];
    *(bf16x4*)(Wb + i) = h;
}

__device__ __forceinline__ void gload_lds16(const void* gsrc, void* lds_dst)
{
    __builtin_amdgcn_global_load_lds(
        (const __attribute__((address_space(1))) unsigned int*)gsrc,
        (__attribute__((address_space(3))) unsigned int*)lds_dst,
        16, 0, 0);
}

__global__ __launch_bounds__(512, 2)
void patch_embed_gemm(const float* __restrict__ x,
                      const __bf16* __restrict__ Wb,
                      const float* __restrict__ bias,
                      float* __restrict__ out)
{
    __shared__ __align__(16) unsigned char lds[2 * BUFB]; // 128 KiB

    // XCD-chunked swizzle (432 % 8 == 0 -> bijective), bm-major so the
    // 3 blocks sharing an A-panel are id-adjacent on one XCD.
    const int h  = blockIdx.x;
    const int l  = (h & 7) * (NBLK / 8) + (h >> 3);
    const int bm = l / GN;
    const int bn = l - bm * GN;

    const int tid  = threadIdx.x;
    const int lane = tid & 63;
    const int wv   = tid >> 6;   // 0..7
    const int wr   = wv >> 2;    // 0..1  -> 128-row strip
    const int wc   = wv & 3;     // 0..3  -> 64-col strip
    const int fr   = lane & 15;
    const int kg   = lane >> 4;

    // ---- A staging map: thread covers rows r0 + 32*it (it=0..7), chunk q
    const int q    = tid & 15;
    const int r0   = tid >> 4;   // 0..31
    const int px   = (q & 3) * 4;
    const int pyo  = q >> 2;
    const int ldsw = r0 * 128 + ((q * 8) ^ ((r0 & 7) << 4));

    int arow[8];
    #pragma unroll
    for (int it = 0; it < 8; ++it) {
        const int m  = bm * BM + r0 + it * 32;
        const int b  = m / Lp;
        const int li = m - b * Lp;
        const int gy = li / GWp;
        const int gx = li - gy * GWp;
        arow[it] = b * (Cch * Him * Wim) + (gy * PB) * Wim + gx * PB;
    }

    // ---- B staging map (global_load_lds, linear LDS dest, swizzled source)
    // issue j: dest byte off = (j*512 + tid)*16 ; row = off>>7 ; b = off&127
    // source fetches W row (bn*256+row), col-bytes (b ^ ((row&7)<<4)) + t*128
    const unsigned char* wbase = (const unsigned char*)(Wb + (size_t)(bn * BN) * Kd);
    int boff[4];   // per-issue row/col source offset (t-invariant part)
    int bdst[4];
    #pragma unroll
    for (int j = 0; j < 4; ++j) {
        const int off = (j * 512 + tid) * 16;
        const int row = off >> 7;
        const int bb  = off & 127;
        boff[j] = row * (Kd * 2) + (bb ^ ((row & 7) << 4));
        bdst[j] = off;
    }

    f32x4 pa[8];

    auto load_A = [&](int t) {
        const int c   = t >> 2;
        const int pyb = (t & 3) * 4;
        const float* xs = x + c * (Him * Wim) + (pyb + pyo) * Wim + px;
        #pragma unroll
        for (int it = 0; it < 8; ++it)
            pa[it] = *(const f32x4*)(xs + arow[it]);
    };

    auto stage_B = [&](int t, int buf) {
        unsigned char* dst = lds + buf * BUFB + ASZ;
        const unsigned char* src = wbase + t * 128;
        #pragma unroll
        for (int j = 0; j < 4; ++j)
            gload_lds16(src + boff[j], dst + bdst[j]);
    };

    auto store_A = [&](int buf) {
        unsigned char* dst = lds + buf * BUFB;
        #pragma unroll
        for (int it = 0; it < 8; ++it) {
            bf16x4 ha;
            #pragma unroll
            for (int e = 0; e < 4; ++e) ha[e] = (__bf16)pa[it][e];
            *(bf16x4*)(dst + ldsw + it * 4096) = ha;
        }
    };

    f32x4 acc[8][4];
    #pragma unroll
    for (int i = 0; i < 8; ++i)
        #pragma unroll
        for (int j = 0; j < 4; ++j)
            acc[i][j] = f32x4{0.f, 0.f, 0.f, 0.f};

    auto compute = [&](int buf) {
        const unsigned char* ldsA = lds + buf * BUFB;
        const unsigned char* ldsB = ldsA + ASZ;
        __builtin_amdgcn_s_setprio(1);
        #pragma unroll
        for (int kk = 0; kk < 2; ++kk) {
            const int kb = kk * 64 + kg * 16;
            bf16x8 br[4];
            #pragma unroll
            for (int f = 0; f < 4; ++f) {
                const int rowB = wc * 64 + f * 16 + fr;
                br[f] = *(const bf16x8*)(ldsB + rowB * 128 + (kb ^ ((rowB & 7) << 4)));
            }
            #pragma unroll
            for (int fi = 0; fi < 8; ++fi) {
                const int rowA = wr * 128 + fi * 16 + fr;
                const bf16x8 ar =
                    *(const bf16x8*)(ldsA + rowA * 128 + (kb ^ ((rowA & 7) << 4)));
                #pragma unroll
                for (int fj = 0; fj < 4; ++fj)
                    acc[fi][fj] = __builtin_amdgcn_mfma_f32_16x16x32_bf16(
                        ar, br[fj], acc[fi][fj], 0, 0, 0);
            }
        }
        __builtin_amdgcn_s_setprio(0);
    };

    // ---- pipelined main loop: 1 barrier per K-step ----
    load_A(0);
    stage_B(0, 0);
    store_A(0);
    __syncthreads();
    int cur = 0;
    for (int t = 0; t < NT - 1; ++t) {
        load_A(t + 1);            // issue A loads (regs)
        stage_B(t + 1, cur ^ 1);  // issue B direct-to-LDS
        compute(cur);
        store_A(cur ^ 1);         // cvt+write A after compute covered latency
        __syncthreads();
        cur ^= 1;
    }
    compute(cur);

    // epilogue: C/D layout col = lane&15, row = (lane>>4)*4 + j
    const int orow0 = bm * BM + wr * 128;
    const int ocol0 = bn * BN + wc * 64;
    #pragma unroll
    for (int fj = 0; fj < 4; ++fj) {
        const int col = ocol0 + fj * 16 + fr;
        const float bv = bias[col];
        #pragma unroll
        for (int fi = 0; fi < 8; ++fi) {
            const int row = orow0 + fi * 16 + kg * 4;
            #pragma unroll
            for (int j = 0; j < 4; ++j)
                out[(row + j) * Nd + col] = acc[fi][fj][j] + bv;
        }
    }
}

} // namespace

extern "C" void kernel_launch(void* const* d_in, const int* in_sizes, int n_in,
                              void* d_out, int out_size, void* d_ws, size_t ws_size,
                              hipStream_t stream)
{
    (void)in_sizes; (void)n_in; (void)out_size; (void)ws_size;
    const float* x  = (const float*)d_in[0];
    const float* Wm = (const float*)d_in[1];
    const float* bs = (const float*)d_in[2];
    float* outp = (float*)d_out;
    __bf16* Wb = (__bf16*)d_ws;   // 768*768*2 B = 1.13 MiB

    convert_w<<<dim3(Kd * Nd / 1024), dim3(256), 0, stream>>>(Wm, Wb);
    patch_embed_gemm<<<dim3(NBLK), dim3(512), 0, stream>>>(x, Wb, bs, outp);
}